// Round 23
// baseline (287.223 us; speedup 1.0000x reference)
//
#include <hip/hip_runtime.h>

#define HID 2048
#define SEQ 2048
#define HD 128
#define QKN 6144      // 3*HID

typedef float f32x4 __attribute__((ext_vector_type(4)));
typedef float f32x16 __attribute__((ext_vector_type(16)));
typedef short s16x8 __attribute__((ext_vector_type(8)));
typedef __bf16 bf16x8 __attribute__((ext_vector_type(8)));

static __device__ __forceinline__ unsigned short f2bf(float x) {
    unsigned u = __float_as_uint(x);
    u = u + 0x7FFFu + ((u >> 16) & 1u);   // RNE
    return (unsigned short)(u >> 16);
}
static __device__ __forceinline__ float bf2f(unsigned short h) {
    return __uint_as_float(((unsigned)h) << 16);
}
static __device__ __forceinline__ bf16x8 as_bf(s16x8 v) {
    union { s16x8 s; bf16x8 b; } u; u.s = v; return u.b;
}
static __device__ __forceinline__ bf16x8 ld_bf8(const unsigned short* p) {
    return as_bf(*(const s16x8*)p);
}
// async global->LDS, 16B/lane; LDS dest = wave-uniform base + lane*16 (m104)
static __device__ __forceinline__ void gload_lds16(const void* g, void* l) {
    __builtin_amdgcn_global_load_lds(
        (const __attribute__((address_space(1))) void*)g,
        (__attribute__((address_space(3))) void*)l,
        16, 0, 0);
}

__global__ __launch_bounds__(256) void fill_f32(
    float* __restrict__ out, float v, int n)
{
    int i = blockIdx.x * 256 + threadIdx.x;
    if (i < n) out[i] = v;
}

// ---------------- fp32 -> bf16 convert (8 elems/thread) ----------------
__global__ __launch_bounds__(256) void convert_f32_bf16(
    const float* __restrict__ in, unsigned short* __restrict__ out)
{
    long i = ((long)blockIdx.x * 256 + threadIdx.x) * 8;
    f32x4 a = *(const f32x4*)&in[i];
    f32x4 b = *(const f32x4*)&in[i + 4];
    s16x8 o;
#pragma unroll
    for (int e = 0; e < 4; ++e) {
        o[e]     = (short)f2bf(a[e]);
        o[e + 4] = (short)f2bf(b[e]);
    }
    *(s16x8*)&out[i] = o;
}

// ------- batched W[k][n] fp32 -> Wt[n][k] bf16 (4 matrices, z selects) ----
__global__ __launch_bounds__(256) void transpose_w4(
    const float* __restrict__ Wq, const float* __restrict__ Wk,
    const float* __restrict__ Wv, const float* __restrict__ Wo,
    unsigned short* __restrict__ wqkvT, unsigned short* __restrict__ woT)
{
    __shared__ float t[32][33];
    const int z = blockIdx.z;
    const float* W = (z == 0) ? Wq : (z == 1) ? Wk : (z == 2) ? Wv : Wo;
    unsigned short* Wt = (z < 3) ? (wqkvT + (long)z * HID * HID) : woT;
    int k0 = blockIdx.x * 32, n0 = blockIdx.y * 32;
    int tx = threadIdx.x & 31, ty = threadIdx.x >> 5;
#pragma unroll
    for (int r = ty; r < 32; r += 8)
        t[r][tx] = W[(long)(k0 + r) * HID + n0 + tx];
    __syncthreads();
#pragma unroll
    for (int r = ty; r < 32; r += 8)
        Wt[(long)(n0 + r) * HID + k0 + tx] = f2bf(t[tx][r]);
}

// ======== 256x(NF*64) single-phase GEMM, fat-wave: wave-tile 128 x NF*16 ====
// dbuf LDS; counted vmcnt(4+NF); setprio; 2-D XCD chunking; write-combined
// epilogue. ROPE=true (QKV): rope fused into epilogue via LDS pair-exchange;
// r23: V heads written TRANSPOSED straight to vtB (v_transpose kernel deleted);
// V rows of qkvB are never written (nothing reads them).
template<int NF, bool F32OUT, bool ROPE>
__global__ __launch_bounds__(512, 2) void gemm_8phase(
    const unsigned short* __restrict__ A,    // [M][K] bf16
    const unsigned short* __restrict__ Bt,   // [N][K] bf16
    const float* __restrict__ bq, const float* __restrict__ bk,
    const float* __restrict__ bv,
    unsigned short* __restrict__ Cb, float* __restrict__ Cf,
    unsigned short* __restrict__ Vt,         // [32][128][SEQ] bf16 (ROPE only)
    int K, int ldc, int nbn, int sm, int sn, int hasBias)
{
    constexpr int BUFE = 16384 + NF * 4096;      // elems per LDS buffer (A|B)
    __shared__ unsigned short lds[2 * BUFE];
    const int tid = threadIdx.x;
    const int wid = tid >> 6, lane = tid & 63;
    const int l16 = lane & 15, l4 = lane >> 4;
    const int wm = wid >> 2, wn = wid & 3;

    // 2-D XCD chunk decode: 8 chunks of sm x sn tiles
    const int bid = blockIdx.x;
    const int xcd = bid & 7, idx = bid >> 3;
    const int ncn = nbn / sn;                    // chunk-cols
    const int cm = xcd / ncn, cn = xcd % ncn;
    const int lm = idx / sn,  ln = idx % sn;
    const long bm = (long)(cm * sm + lm) * 256;
    const long bn = (long)(cn * sn + ln) * (NF * 64);

    const int NT = K >> 6;
    const long strideB = (long)K * 2;            // bytes per global row
    const int srow = tid >> 3;                   // 0..63 row within 64-row chunk
    const int scb  = ((tid & 7) * 16) ^ ((srow & 7) << 4);   // pre-swizzled src byte

    auto stageA = [&](int t, int c) {            // c in 0..3
        unsigned short* base = &lds[(t & 1) * BUFE];
        const int row = c * 64 + srow;
        const char* src = (const char*)A + (bm + row) * strideB + (long)t * 128 + scb;
        gload_lds16(src, base + (c * 64 + wid * 8) * 64);
    };
    auto stageB = [&](int t, int c) {            // c in 0..NF-1
        unsigned short* base = &lds[(t & 1) * BUFE + 16384];
        const int row = c * 64 + srow;
        const char* src = (const char*)Bt + (bn + row) * strideB + (long)t * 128 + scb;
        gload_lds16(src, base + (c * 64 + wid * 8) * 64);
    };

    f32x4 acc[8][NF];
#pragma unroll
    for (int i = 0; i < 8; ++i)
#pragma unroll
        for (int j = 0; j < NF; ++j) acc[i][j] = f32x4{0.f, 0.f, 0.f, 0.f};

    // compute one K-tile: kk-outer so only one kk's fragments are live at once
    auto compute = [&](const unsigned short* Ab, const unsigned short* Bb) {
#pragma unroll
        for (int kk = 0; kk < 2; ++kk) {
            bf16x8 bfr[NF];
#pragma unroll
            for (int j = 0; j < NF; ++j) {
                const int row = wn * (NF * 16) + j * 16 + l16;
                const char* rb = (const char*)Bb + row * 128;
                bfr[j] = as_bf(*(const s16x8*)(rb + ((kk * 64 + l4 * 16) ^ ((l16 & 7) << 4))));
            }
#pragma unroll
            for (int half = 0; half < 2; ++half) {
                bf16x8 af[4];
#pragma unroll
                for (int i = 0; i < 4; ++i) {
                    const int row = wm * 128 + (half * 4 + i) * 16 + l16;
                    const char* rb = (const char*)Ab + row * 128;
                    af[i] = as_bf(*(const s16x8*)(rb + ((kk * 64 + l4 * 16) ^ ((l16 & 7) << 4))));
                }
                __builtin_amdgcn_s_setprio(1);
#pragma unroll
                for (int i = 0; i < 4; ++i)
#pragma unroll
                    for (int j = 0; j < NF; ++j)
                        acc[half * 4 + i][j] = __builtin_amdgcn_mfma_f32_16x16x32_bf16(
                            af[i], bfr[j], acc[half * 4 + i][j], 0, 0, 0);
                __builtin_amdgcn_s_setprio(0);
            }
        }
    };

    // prologue: stage tile 0 fully (4+NF loads/thread)
#pragma unroll
    for (int c = 0; c < 4; ++c) stageA(0, c);
#pragma unroll
    for (int c = 0; c < NF; ++c) stageB(0, c);

    for (int t = 0; t < NT - 1; ++t) {
        const unsigned short* Ab = &lds[(t & 1) * BUFE];
        const unsigned short* Bb = Ab + 16384;
#pragma unroll
        for (int c = 0; c < 4; ++c) stageA(t + 1, c);
#pragma unroll
        for (int c = 0; c < NF; ++c) stageB(t + 1, c);
        __builtin_amdgcn_sched_barrier(0);
        // counted wait: tile t's (4+NF) loads done, tile t+1's in flight
        if constexpr (NF == 6)      asm volatile("s_waitcnt vmcnt(10)" ::: "memory");
        else if constexpr (NF == 3) asm volatile("s_waitcnt vmcnt(7)" ::: "memory");
        else                        asm volatile("s_waitcnt vmcnt(6)" ::: "memory");
        __builtin_amdgcn_s_barrier();
        __builtin_amdgcn_sched_barrier(0);                 // no ds_read above validity
        compute(Ab, Bb);
        __builtin_amdgcn_s_barrier();   // all reads of buf done before t+2 staging
    }
    {
        const unsigned short* Ab = &lds[((NT - 1) & 1) * BUFE];
        const unsigned short* Bb = Ab + 16384;
        asm volatile("s_waitcnt vmcnt(0)" ::: "memory");
        __builtin_amdgcn_s_barrier();
        __builtin_amdgcn_sched_barrier(0);
        compute(Ab, Bb);
    }

    // bias per owned column
    float bvv[NF];
#pragma unroll
    for (int nf = 0; nf < NF; ++nf) {
        const long n = bn + wn * (NF * 16) + nf * 16 + l16;
        bvv[nf] = 0.f;
        if (hasBias)
            bvv[nf] = (n < HID) ? bq[n] : ((n < 2 * HID) ? bk[n - HID] : bv[n - 2 * HID]);
    }

    if constexpr (ROPE) {
        // fused RoPE + V-transpose epilogue: 4 row-chunks of 64.
        // acc+bias -> LDS fp32 [64][385]; Q/K rope-rotated (Q scaled by
        // (1/sqrt(128))*log2(e)) and stored to Cb; V heads stored TRANSPOSED
        // to Vt[bh][d][s] via ushort2 (coalesced along s), Cb write skipped.
        constexpr int NH = NF / 2;               // whole heads per block (3 for NF=6)
        float* fl = (float*)lds;                 // reuse staging LDS (64*385*4 B)
        const int jr = tid & 63;
        const int rquo = tid >> 6;               // 0..7
        const int sp = (tid & 31) * 2;           // s-pair within chunk (V pass)
        const int dg = tid >> 5;                 // 0..15 (V pass)
        const float inv = exp2f(-(float)jr * 0.20762050593046f);  // 10000^(-j/64)
#pragma unroll
        for (int c = 0; c < 4; ++c) {
            __builtin_amdgcn_s_barrier();        // prior chunk reads / final compute done
            if (wm == (c >> 1)) {
                const int mf0 = (c & 1) * 4;
#pragma unroll
                for (int mfi = 0; mfi < 4; ++mfi)
#pragma unroll
                    for (int r = 0; r < 4; ++r) {
                        const int rl = mfi * 16 + l4 * 4 + r;
#pragma unroll
                        for (int nf = 0; nf < NF; ++nf)
                            fl[rl * 385 + wn * (NF * 16) + nf * 16 + l16] =
                                acc[mf0 + mfi][nf][r] + bvv[nf];
                    }
            }
            __builtin_amdgcn_s_barrier();
            const long mrow0 = bm + (c >> 1) * 128 + (c & 1) * 64;   // chunk base row
            // Q/K rope pass
#pragma unroll
            for (int rr = 0; rr < 8; ++rr) {
                const int rl = rr * 8 + rquo;
                const long m = mrow0 + rl;
                const int s = (int)(m & (SEQ - 1));
                float sn, cs;
                sincosf((float)s * inv, &sn, &cs);
#pragma unroll
                for (int hh = 0; hh < NH; ++hh) {
                    const long n0 = bn + hh * 128;
                    if (n0 >= 2 * HID) continue;           // V handled below
                    const long n = n0 + jr;
                    const float qsv = (n0 < HID) ? 0.12751744581845f : 1.0f;
                    const float x1 = fl[rl * 385 + hh * 128 + jr];
                    const float x2 = fl[rl * 385 + hh * 128 + jr + 64];
                    Cb[m * (long)ldc + n]      = f2bf((x1 * cs - x2 * sn) * qsv);
                    Cb[m * (long)ldc + n + 64] = f2bf((x2 * cs + x1 * sn) * qsv);
                }
            }
            // V transposed pass: Vt[(bh*128+d)*SEQ + s], ushort2 along s
#pragma unroll
            for (int hh = 0; hh < NH; ++hh) {
                const long n0 = bn + hh * 128;
                if (n0 < 2 * HID) continue;
                const int bb = (int)(mrow0 >> 11);                   // batch
                const int sg = (int)(mrow0 & (SEQ - 1)) + sp;
                const long bh2 = (long)bb * 16 + (int)((n0 - 2 * HID) >> 7);
#pragma unroll
                for (int db = 0; db < 8; ++db) {
                    const int d = db * 16 + dg;
                    union { unsigned short s2[2]; unsigned u; } w;
                    w.s2[0] = f2bf(fl[sp       * 385 + hh * 128 + d]);
                    w.s2[1] = f2bf(fl[(sp + 1) * 385 + hh * 128 + d]);
                    *(unsigned*)&Vt[(bh2 * HD + d) * SEQ + sg] = w.u;
                }
            }
        }
    } else {
        // plain epilogue: row-outer / nf-inner (write combining)
#pragma unroll
        for (int mf = 0; mf < 8; ++mf) {
#pragma unroll
            for (int r = 0; r < 4; ++r) {
                const long m = bm + wm * 128 + mf * 16 + l4 * 4 + r;
#pragma unroll
                for (int nf = 0; nf < NF; ++nf) {
                    const long n = bn + wn * (NF * 16) + nf * 16 + l16;
                    float v = acc[mf][nf][r] + bvv[nf];
                    if (F32OUT) Cf[m * (long)ldc + n] = v;
                    else        Cb[m * (long)ldc + n] = f2bf(v);
                }
            }
        }
    }
}

// -------- MFMA flash attention (r22): 32x32x16 shape, 8 waves x 32 q
// (QBLK=256). T2 swizzles, dbuf, defer-max, log2-domain, swapped-QK^T
// in-register softmax. XCD-chunked: 4 heads x 8 q-tiles per XCD.
__global__ __launch_bounds__(512, 2) void attn_kernel(
    const unsigned short* __restrict__ qkv,
    const unsigned short* __restrict__ vt,
    unsigned short* __restrict__ attnout)
{
    __shared__ unsigned short Ks[2][64 * 128];   // [kv][d], byte ^= (kv&7)<<4
    __shared__ unsigned short Vs[2][128 * 64];   // [d][kv], byte ^= (d&7)<<4

    const int tid = threadIdx.x, wid = tid >> 6, lane = tid & 63;
    const int l32 = lane & 31, hh = lane >> 5;
    const int l16 = lane & 15, l4 = lane >> 4;   // staging only
    const int bid = blockIdx.x;                  // 0..255
    const int xcd = bid & 7, idx = bid >> 3;     // idx 0..31
    const int bh = xcd * 4 + (idx >> 3);         // 4 heads per XCD
    const int qt = idx & 7;                      // 8 q-tiles (QBLK=256)
    const int b = bh >> 4, h = bh & 15;
    const long rowbase = (long)b * SEQ;

    const unsigned short* Kg = &qkv[rowbase * QKN + HID + h * HD];  // + s*QKN
    const unsigned short* Vg = &vt[(long)bh * HD * SEQ];            // + d*SEQ

    auto stage = [&](int buf, int kv0) {
#pragma unroll
        for (int i = 0; i < 2; ++i) {
            int c = wid * 2 + i;
            int kr = c * 4 + l4;
            int kcb = (l16 * 16) ^ ((kr & 7) << 4);
            gload_lds16((const char*)(Kg + (long)(kv0 + kr) * QKN) + kcb, &Ks[buf][c * 512]);
            int vr = c * 8 + (lane >> 3);
            int vcb = ((lane & 7) * 16) ^ ((vr & 7) << 4);
            gload_lds16((const char*)(Vg + (long)vr * SEQ + kv0) + vcb, &Vs[buf][c * 512]);
        }
    };

    // Q as B operand: q-col = l32, k = ks*16 + hh*8 + e (8 k-steps of 16)
    bf16x8 qf[8];
    {
        const long qrow = rowbase + qt * 256 + wid * 32 + l32;
        const unsigned short* qp = &qkv[qrow * QKN + h * HD];
#pragma unroll
        for (int ks = 0; ks < 8; ++ks)
            qf[ks] = ld_bf8(qp + ks * 16 + hh * 8);
    }

    f32x16 ob[4];
#pragma unroll
    for (int db = 0; db < 4; ++db)
#pragma unroll
        for (int r = 0; r < 16; ++r) ob[db][r] = 0.f;
    float mrun = -3.0e38f, lrun = 0.f;       // per-lane scalars (q = l32), log2 units

    stage(0, 0);
    __syncthreads();

    for (int t = 0; t < SEQ / 64; ++t) {
        const int cur = t & 1;
        if (t < SEQ / 64 - 1) stage(cur ^ 1, (t + 1) * 64);
        __builtin_amdgcn_sched_barrier(0);   // pin: issue next-tile stage first

        const unsigned short* Kc = &Ks[cur][0];
        const unsigned short* Vc = &Vs[cur][0];

        // S^T = K Q^T (log2 domain): 2 kv-blocks of 32, K=128 in 8 steps
        f32x16 sc[2];
#pragma unroll
        for (int kb = 0; kb < 2; ++kb)
#pragma unroll
            for (int r = 0; r < 16; ++r) sc[kb][r] = 0.f;
#pragma unroll
        for (int ks = 0; ks < 8; ++ks) {
#pragma unroll
            for (int kb = 0; kb < 2; ++kb) {
                int row = kb * 32 + l32;
                int cb = (ks * 32 + hh * 16) ^ ((row & 7) << 4);
                bf16x8 kf = as_bf(*(const s16x8*)((const char*)Kc + row * 256 + cb));
                sc[kb] = __builtin_amdgcn_mfma_f32_32x32x16_bf16(kf, qf[ks], sc[kb], 0, 0, 0);
            }
        }

        // per-lane max over 32 values, then combine lane pair (l, l^32)
        float tmax = sc[0][0];
#pragma unroll
        for (int kb = 0; kb < 2; ++kb)
#pragma unroll
            for (int r = 0; r < 16; ++r) tmax = fmaxf(tmax, sc[kb][r]);
        tmax = fmaxf(tmax, __shfl_xor(tmax, 32, 64));

        // defer-max (T13, log2 units): skip rescale when growth <= 8
        if (!__all(tmax - mrun <= 8.0f)) {
            float mn = fmaxf(mrun, tmax);
            float e_ = exp2f(mrun - mn);
            mrun = mn;
            lrun *= e_;
            float sr[16];
#pragma unroll
            for (int r = 0; r < 16; ++r)
                sr[r] = __shfl(e_, (r & 3) + 8 * (r >> 2) + 4 * hh, 64);
#pragma unroll
            for (int db = 0; db < 4; ++db)
#pragma unroll
                for (int r = 0; r < 16; ++r) ob[db][r] *= sr[r];
        }

        // P = exp2(S - m); pack to bf16 pairs; sum
        unsigned pk[2][8];
        float sum = 0.f;
#pragma unroll
        for (int kb = 0; kb < 2; ++kb) {
#pragma unroll
            for (int g = 0; g < 8; ++g) {
                float p0 = exp2f(sc[kb][2 * g]     - mrun);
                float p1 = exp2f(sc[kb][2 * g + 1] - mrun);
                sum += p0 + p1;
                union { __bf16 b[2]; unsigned u; } w;
                w.b[0] = (__bf16)p0; w.b[1] = (__bf16)p1;
                pk[kb][g] = w.u;
            }
        }
        sum += __shfl_xor(sum, 32, 64);
        lrun += sum;

        // PV A-fragments: pa[ks] elem e -> P[q=l32][kv = ks*16 + hh*8 + e]
        union { unsigned u[4]; bf16x8 v; } pa[4];
#pragma unroll
        for (int ks = 0; ks < 4; ++ks) {
            const int kb = ks >> 1, base = (ks & 1) * 4;
            unsigned a0 = __shfl_xor(pk[kb][base + 0], 32, 64);
            unsigned a1 = __shfl_xor(pk[kb][base + 1], 32, 64);
            unsigned a2 = __shfl_xor(pk[kb][base + 2], 32, 64);
            unsigned a3 = __shfl_xor(pk[kb][base + 3], 32, 64);
            pa[ks].u[0] = hh ? a2 : pk[kb][base + 0];
            pa[ks].u[1] = hh ? a3 : pk[kb][base + 1];
            pa[ks].u[2] = hh ? pk[kb][base + 2] : a0;
            pa[ks].u[3] = hh ? pk[kb][base + 3] : a1;
        }

        // O += P V: B = V^T[d][kv] swizzled; 4 d-blocks x 4 kv-steps
#pragma unroll
        for (int ks = 0; ks < 4; ++ks) {
#pragma unroll
            for (int db = 0; db < 4; ++db) {
                int row = db * 32 + l32;
                int cb = (ks * 32 + hh * 16) ^ ((row & 7) << 4);
                bf16x8 vb = as_bf(*(const s16x8*)((const char*)Vc + row * 128 + cb));
                ob[db] = __builtin_amdgcn_mfma_f32_32x32x16_bf16(pa[ks].v, vb, ob[db], 0, 0, 0);
            }
        }
        __syncthreads();   // implicit vmcnt(0): next-tile stage (issued pre-compute) done
    }

    // stats at q=l32 lanes; ob rows are q=(r&3)+8*(r>>2)+4*hh -> hop via shuffles
    float linv = 1.f / lrun;
    float li[16];
#pragma unroll
    for (int r = 0; r < 16; ++r)
        li[r] = __shfl(linv, (r & 3) + 8 * (r >> 2) + 4 * hh, 64);
#pragma unroll
    for (int db = 0; db < 4; ++db) {
#pragma unroll
        for (int r = 0; r < 16; ++r) {
            const long m = rowbase + qt * 256 + wid * 32 + (r & 3) + 8 * (r >> 2) + 4 * hh;
            attnout[m * HID + h * HD + db * 32 + l32] = f2bf(ob[db][r] * li[r]);
        }
    }
}

// ---------------- launch ----------------
extern "C" void kernel_launch(void* const* d_in, const int* in_sizes, int n_in,
                              void* d_out, int out_size, void* d_ws, size_t ws_size,
                              hipStream_t stream)
{
    const float* hs = (const float*)d_in[0];
    const float* Wq = (const float*)d_in[1];
    const float* bq = (const float*)d_in[2];
    const float* Wk = (const float*)d_in[3];
    const float* bk = (const float*)d_in[4];
    const float* Wv = (const float*)d_in[5];
    const float* bv = (const float*)d_in[6];
    const float* Wo = (const float*)d_in[7];
    float* out = (float*)d_out;   // fp32 output (confirmed round 5)

    bool shapes_ok =
        (n_in == 8) && (out_size == 8388608) &&
        in_sizes[0] == 8388608 && in_sizes[1] == 4194304 && in_sizes[2] == 2048 &&
        in_sizes[3] == 4194304 && in_sizes[4] == 2048 && in_sizes[5] == 4194304 &&
        in_sizes[6] == 2048 && in_sizes[7] == 4194304;
    if (!shapes_ok || ws_size < 117440512ull) {
        fill_f32<<<32768, 256, 0, stream>>>(out, shapes_ok ? 1000.f : 0.f, out_size);
        return;
    }

    char* ws = (char*)d_ws;
    unsigned short* hsB     = (unsigned short*)(ws);              // [4096][2048] bf16
    unsigned short* qkvB    = (unsigned short*)(ws + 16777216);   // [4096][6144] bf16
    unsigned short* wqkvT   = (unsigned short*)(ws + 67108864);   // [6144][2048] bf16
    unsigned short* vtB     = (unsigned short*)(ws + 92274688);   // [32][128][2048] bf16
    unsigned short* woT     = (unsigned short*)(ws + 109051904);  // [2048][2048] bf16
    unsigned short* attnout = hsB;   // hsB dead after QKV GEMM

    convert_f32_bf16<<<4096, 256, 0, stream>>>(hs, hsB);
    transpose_w4<<<dim3(64, 64, 4), 256, 0, stream>>>(Wq, Wk, Wv, Wo, wqkvT, woT);

    // QKV fat-wave + fused RoPE + V-transpose epilogue: 256 blocks = 1 round
    gemm_8phase<6, false, true><<<dim3(256), 512, 0, stream>>>(
        hsB, wqkvT, bq, bk, bv, qkvB, nullptr, vtB, 2048, QKN, 16, 8, 4, 1);
    // attn: 32x32 shape, QBLK=256, 8 waves x 32 q, 256 blocks = 1 round
    attn_kernel<<<dim3(256), 512, 0, stream>>>(qkvB, vtB, attnout);
    // out-proj: 256x128 tiles, 16x16 grid, XCD chunks 4x8, fp32 out
    gemm_8phase<2, true, false><<<dim3(256), 512, 0, stream>>>(
        attnout, woT, nullptr, nullptr, nullptr, nullptr, out, nullptr, 2048, HID, 16, 4, 8, 0);
}

// Round 24
// 285.337 us; speedup vs baseline: 1.0066x; 1.0066x over previous
//
#include <hip/hip_runtime.h>

#define HID 2048
#define SEQ 2048
#define HD 128
#define QKN 6144      // 3*HID

typedef float f32x4 __attribute__((ext_vector_type(4)));
typedef float f32x16 __attribute__((ext_vector_type(16)));
typedef short s16x8 __attribute__((ext_vector_type(8)));
typedef __bf16 bf16x8 __attribute__((ext_vector_type(8)));

static __device__ __forceinline__ unsigned short f2bf(float x) {
    unsigned u = __float_as_uint(x);
    u = u + 0x7FFFu + ((u >> 16) & 1u);   // RNE
    return (unsigned short)(u >> 16);
}
static __device__ __forceinline__ float bf2f(unsigned short h) {
    return __uint_as_float(((unsigned)h) << 16);
}
static __device__ __forceinline__ bf16x8 as_bf(s16x8 v) {
    union { s16x8 s; bf16x8 b; } u; u.s = v; return u.b;
}
static __device__ __forceinline__ bf16x8 ld_bf8(const unsigned short* p) {
    return as_bf(*(const s16x8*)p);
}
// async global->LDS, 16B/lane; LDS dest = wave-uniform base + lane*16 (m104)
static __device__ __forceinline__ void gload_lds16(const void* g, void* l) {
    __builtin_amdgcn_global_load_lds(
        (const __attribute__((address_space(1))) void*)g,
        (__attribute__((address_space(3))) void*)l,
        16, 0, 0);
}

__global__ __launch_bounds__(256) void fill_f32(
    float* __restrict__ out, float v, int n)
{
    int i = blockIdx.x * 256 + threadIdx.x;
    if (i < n) out[i] = v;
}

// ---------------- fp32 -> bf16 convert (8 elems/thread) ----------------
__global__ __launch_bounds__(256) void convert_f32_bf16(
    const float* __restrict__ in, unsigned short* __restrict__ out)
{
    long i = ((long)blockIdx.x * 256 + threadIdx.x) * 8;
    f32x4 a = *(const f32x4*)&in[i];
    f32x4 b = *(const f32x4*)&in[i + 4];
    s16x8 o;
#pragma unroll
    for (int e = 0; e < 4; ++e) {
        o[e]     = (short)f2bf(a[e]);
        o[e + 4] = (short)f2bf(b[e]);
    }
    *(s16x8*)&out[i] = o;
}

// ------- batched W[k][n] fp32 -> Wt[n][k] bf16 (4 matrices, z selects) ----
__global__ __launch_bounds__(256) void transpose_w4(
    const float* __restrict__ Wq, const float* __restrict__ Wk,
    const float* __restrict__ Wv, const float* __restrict__ Wo,
    unsigned short* __restrict__ wqkvT, unsigned short* __restrict__ woT)
{
    __shared__ float t[32][33];
    const int z = blockIdx.z;
    const float* W = (z == 0) ? Wq : (z == 1) ? Wk : (z == 2) ? Wv : Wo;
    unsigned short* Wt = (z < 3) ? (wqkvT + (long)z * HID * HID) : woT;
    int k0 = blockIdx.x * 32, n0 = blockIdx.y * 32;
    int tx = threadIdx.x & 31, ty = threadIdx.x >> 5;
#pragma unroll
    for (int r = ty; r < 32; r += 8)
        t[r][tx] = W[(long)(k0 + r) * HID + n0 + tx];
    __syncthreads();
#pragma unroll
    for (int r = ty; r < 32; r += 8)
        Wt[(long)(n0 + r) * HID + k0 + tx] = f2bf(t[tx][r]);
}

// ======== 256x(NF*64) single-phase GEMM, fat-wave: wave-tile 128 x NF*16 ====
// dbuf LDS; counted vmcnt(4+NF); setprio; 2-D XCD chunking; write-combined
// epilogue. ROPE=true (QKV): rope fused into epilogue via LDS pair-exchange.
template<int NF, bool F32OUT, bool ROPE>
__global__ __launch_bounds__(512, 2) void gemm_8phase(
    const unsigned short* __restrict__ A,    // [M][K] bf16
    const unsigned short* __restrict__ Bt,   // [N][K] bf16
    const float* __restrict__ bq, const float* __restrict__ bk,
    const float* __restrict__ bv,
    unsigned short* __restrict__ Cb, float* __restrict__ Cf,
    int K, int ldc, int nbn, int sm, int sn, int hasBias)
{
    constexpr int BUFE = 16384 + NF * 4096;      // elems per LDS buffer (A|B)
    __shared__ unsigned short lds[2 * BUFE];
    const int tid = threadIdx.x;
    const int wid = tid >> 6, lane = tid & 63;
    const int l16 = lane & 15, l4 = lane >> 4;
    const int wm = wid >> 2, wn = wid & 3;

    // 2-D XCD chunk decode: 8 chunks of sm x sn tiles
    const int bid = blockIdx.x;
    const int xcd = bid & 7, idx = bid >> 3;
    const int ncn = nbn / sn;                    // chunk-cols
    const int cm = xcd / ncn, cn = xcd % ncn;
    const int lm = idx / sn,  ln = idx % sn;
    const long bm = (long)(cm * sm + lm) * 256;
    const long bn = (long)(cn * sn + ln) * (NF * 64);

    const int NT = K >> 6;
    const long strideB = (long)K * 2;            // bytes per global row
    const int srow = tid >> 3;                   // 0..63 row within 64-row chunk
    const int scb  = ((tid & 7) * 16) ^ ((srow & 7) << 4);   // pre-swizzled src byte

    auto stageA = [&](int t, int c) {            // c in 0..3
        unsigned short* base = &lds[(t & 1) * BUFE];
        const int row = c * 64 + srow;
        const char* src = (const char*)A + (bm + row) * strideB + (long)t * 128 + scb;
        gload_lds16(src, base + (c * 64 + wid * 8) * 64);
    };
    auto stageB = [&](int t, int c) {            // c in 0..NF-1
        unsigned short* base = &lds[(t & 1) * BUFE + 16384];
        const int row = c * 64 + srow;
        const char* src = (const char*)Bt + (bn + row) * strideB + (long)t * 128 + scb;
        gload_lds16(src, base + (c * 64 + wid * 8) * 64);
    };

    f32x4 acc[8][NF];
#pragma unroll
    for (int i = 0; i < 8; ++i)
#pragma unroll
        for (int j = 0; j < NF; ++j) acc[i][j] = f32x4{0.f, 0.f, 0.f, 0.f};

    // compute one K-tile: kk-outer so only one kk's fragments are live at once
    auto compute = [&](const unsigned short* Ab, const unsigned short* Bb) {
#pragma unroll
        for (int kk = 0; kk < 2; ++kk) {
            bf16x8 bfr[NF];
#pragma unroll
            for (int j = 0; j < NF; ++j) {
                const int row = wn * (NF * 16) + j * 16 + l16;
                const char* rb = (const char*)Bb + row * 128;
                bfr[j] = as_bf(*(const s16x8*)(rb + ((kk * 64 + l4 * 16) ^ ((l16 & 7) << 4))));
            }
#pragma unroll
            for (int half = 0; half < 2; ++half) {
                bf16x8 af[4];
#pragma unroll
                for (int i = 0; i < 4; ++i) {
                    const int row = wm * 128 + (half * 4 + i) * 16 + l16;
                    const char* rb = (const char*)Ab + row * 128;
                    af[i] = as_bf(*(const s16x8*)(rb + ((kk * 64 + l4 * 16) ^ ((l16 & 7) << 4))));
                }
                __builtin_amdgcn_s_setprio(1);
#pragma unroll
                for (int i = 0; i < 4; ++i)
#pragma unroll
                    for (int j = 0; j < NF; ++j)
                        acc[half * 4 + i][j] = __builtin_amdgcn_mfma_f32_16x16x32_bf16(
                            af[i], bfr[j], acc[half * 4 + i][j], 0, 0, 0);
                __builtin_amdgcn_s_setprio(0);
            }
        }
    };

    // prologue: stage tile 0 fully (4+NF loads/thread)
#pragma unroll
    for (int c = 0; c < 4; ++c) stageA(0, c);
#pragma unroll
    for (int c = 0; c < NF; ++c) stageB(0, c);

    for (int t = 0; t < NT - 1; ++t) {
        const unsigned short* Ab = &lds[(t & 1) * BUFE];
        const unsigned short* Bb = Ab + 16384;
#pragma unroll
        for (int c = 0; c < 4; ++c) stageA(t + 1, c);
#pragma unroll
        for (int c = 0; c < NF; ++c) stageB(t + 1, c);
        __builtin_amdgcn_sched_barrier(0);
        // counted wait: tile t's (4+NF) loads done, tile t+1's in flight
        if constexpr (NF == 6)      asm volatile("s_waitcnt vmcnt(10)" ::: "memory");
        else if constexpr (NF == 3) asm volatile("s_waitcnt vmcnt(7)" ::: "memory");
        else                        asm volatile("s_waitcnt vmcnt(6)" ::: "memory");
        __builtin_amdgcn_s_barrier();
        __builtin_amdgcn_sched_barrier(0);                 // no ds_read above validity
        compute(Ab, Bb);
        __builtin_amdgcn_s_barrier();   // all reads of buf done before t+2 staging
    }
    {
        const unsigned short* Ab = &lds[((NT - 1) & 1) * BUFE];
        const unsigned short* Bb = Ab + 16384;
        asm volatile("s_waitcnt vmcnt(0)" ::: "memory");
        __builtin_amdgcn_s_barrier();
        __builtin_amdgcn_sched_barrier(0);
        compute(Ab, Bb);
    }

    // bias per owned column
    float bvv[NF];
#pragma unroll
    for (int nf = 0; nf < NF; ++nf) {
        const long n = bn + wn * (NF * 16) + nf * 16 + l16;
        bvv[nf] = 0.f;
        if (hasBias)
            bvv[nf] = (n < HID) ? bq[n] : ((n < 2 * HID) ? bk[n - HID] : bv[n - 2 * HID]);
    }

    if constexpr (ROPE) {
        // fused RoPE epilogue: 4 row-chunks of 64; acc+bias -> LDS fp32 [64][385];
        // pairs (j, j+64) rotated in fp32; Q scaled by (1/sqrt(128))*log2(e);
        // V heads pass through. Coalesced bf16 stores.
        constexpr int NH = NF / 2;               // whole heads per block (3 for NF=6)
        float* fl = (float*)lds;                 // reuse staging LDS (64*385*4 B)
        const int jr = tid & 63;
        const int rquo = tid >> 6;               // 0..7
        const float inv = exp2f(-(float)jr * 0.20762050593046f);  // 10000^(-j/64)
#pragma unroll
        for (int c = 0; c < 4; ++c) {
            __builtin_amdgcn_s_barrier();        // prior chunk reads / final compute done
            if (wm == (c >> 1)) {
                const int mf0 = (c & 1) * 4;
#pragma unroll
                for (int mfi = 0; mfi < 4; ++mfi)
#pragma unroll
                    for (int r = 0; r < 4; ++r) {
                        const int rl = mfi * 16 + l4 * 4 + r;
#pragma unroll
                        for (int nf = 0; nf < NF; ++nf)
                            fl[rl * 385 + wn * (NF * 16) + nf * 16 + l16] =
                                acc[mf0 + mfi][nf][r] + bvv[nf];
                    }
            }
            __builtin_amdgcn_s_barrier();
#pragma unroll
            for (int rr = 0; rr < 8; ++rr) {
                const int rl = rr * 8 + rquo;
                const long m = bm + (c >> 1) * 128 + (c & 1) * 64 + rl;
                const int s = (int)(m & (SEQ - 1));
                float sn, cs;
                sincosf((float)s * inv, &sn, &cs);
#pragma unroll
                for (int hh = 0; hh < NH; ++hh) {
                    const long n = bn + hh * 128 + jr;
                    const bool ron = n < 2 * HID;          // rope Q,K; V passthrough
                    const float qsv = (n < HID) ? 0.12751744581845f : 1.0f;
                    const float se = ron ? sn : 0.f;
                    const float ce = ron ? cs : 1.f;
                    const float x1 = fl[rl * 385 + hh * 128 + jr];
                    const float x2 = fl[rl * 385 + hh * 128 + jr + 64];
                    Cb[m * (long)ldc + n]      = f2bf((x1 * ce - x2 * se) * qsv);
                    Cb[m * (long)ldc + n + 64] = f2bf((x2 * ce + x1 * se) * qsv);
                }
            }
        }
    } else {
        // plain epilogue: row-outer / nf-inner (write combining)
#pragma unroll
        for (int mf = 0; mf < 8; ++mf) {
#pragma unroll
            for (int r = 0; r < 4; ++r) {
                const long m = bm + wm * 128 + mf * 16 + l4 * 4 + r;
#pragma unroll
                for (int nf = 0; nf < NF; ++nf) {
                    const long n = bn + wn * (NF * 16) + nf * 16 + l16;
                    float v = acc[mf][nf][r] + bvv[nf];
                    if (F32OUT) Cf[m * (long)ldc + n] = v;
                    else        Cb[m * (long)ldc + n] = f2bf(v);
                }
            }
        }
    }
}

// ---------------- V[b,s,h,d] -> VT[b,h,d,s] ----------------
__global__ __launch_bounds__(256) void v_transpose(
    const unsigned short* __restrict__ qkv, unsigned short* __restrict__ vt)
{
    __shared__ unsigned short t[32][33];
    int bh = blockIdx.z;
    int b = bh >> 4, h = bh & 15;
    int s0 = blockIdx.x * 32, d0 = blockIdx.y * 32;
    int tx = threadIdx.x & 31, ty = threadIdx.x >> 5;
#pragma unroll
    for (int r = ty; r < 32; r += 8)
        t[r][tx] = qkv[(long)(b * SEQ + s0 + r) * QKN + 2 * HID + h * HD + d0 + tx];
    __syncthreads();
#pragma unroll
    for (int r = ty; r < 32; r += 8)
        vt[((long)bh * HD + d0 + r) * SEQ + s0 + tx] = t[tx][r];
}

// -------- MFMA flash attention (r22 best): 32x32x16 shape, 8 waves x 32 q
// (QBLK=256). Per-fragment LDS read serves 32 q-rows. S^T lane layout:
// q = lane&31 -> per-lane scalar stats, single shfl_xor(32) reduce.
// C/D map col=lane&31, row=(reg&3)+8*(reg>>2)+4*(lane>>5) (m74/m101).
// T2 swizzles, dbuf, defer-max, log2-domain. XCD-chunked.
__global__ __launch_bounds__(512, 2) void attn_kernel(
    const unsigned short* __restrict__ qkv,
    const unsigned short* __restrict__ vt,
    unsigned short* __restrict__ attnout)
{
    __shared__ unsigned short Ks[2][64 * 128];   // [kv][d], byte ^= (kv&7)<<4
    __shared__ unsigned short Vs[2][128 * 64];   // [d][kv], byte ^= (d&7)<<4

    const int tid = threadIdx.x, wid = tid >> 6, lane = tid & 63;
    const int l32 = lane & 31, hh = lane >> 5;
    const int l16 = lane & 15, l4 = lane >> 4;   // staging only
    const int bid = blockIdx.x;                  // 0..255
    const int xcd = bid & 7, idx = bid >> 3;     // idx 0..31
    const int bh = xcd * 4 + (idx >> 3);         // 4 heads per XCD
    const int qt = idx & 7;                      // 8 q-tiles (QBLK=256)
    const int b = bh >> 4, h = bh & 15;
    const long rowbase = (long)b * SEQ;

    const unsigned short* Kg = &qkv[rowbase * QKN + HID + h * HD];  // + s*QKN
    const unsigned short* Vg = &vt[(long)bh * HD * SEQ];            // + d*SEQ

    auto stage = [&](int buf, int kv0) {
#pragma unroll
        for (int i = 0; i < 2; ++i) {
            int c = wid * 2 + i;
            int kr = c * 4 + l4;
            int kcb = (l16 * 16) ^ ((kr & 7) << 4);
            gload_lds16((const char*)(Kg + (long)(kv0 + kr) * QKN) + kcb, &Ks[buf][c * 512]);
            int vr = c * 8 + (lane >> 3);
            int vcb = ((lane & 7) * 16) ^ ((vr & 7) << 4);
            gload_lds16((const char*)(Vg + (long)vr * SEQ + kv0) + vcb, &Vs[buf][c * 512]);
        }
    };

    // Q as B operand: q-col = l32, k = ks*16 + hh*8 + e (8 k-steps of 16)
    bf16x8 qf[8];
    {
        const long qrow = rowbase + qt * 256 + wid * 32 + l32;
        const unsigned short* qp = &qkv[qrow * QKN + h * HD];
#pragma unroll
        for (int ks = 0; ks < 8; ++ks)
            qf[ks] = ld_bf8(qp + ks * 16 + hh * 8);
    }

    f32x16 ob[4];
#pragma unroll
    for (int db = 0; db < 4; ++db)
#pragma unroll
        for (int r = 0; r < 16; ++r) ob[db][r] = 0.f;
    float mrun = -3.0e38f, lrun = 0.f;       // per-lane scalars (q = l32), log2 units

    stage(0, 0);
    __syncthreads();

    for (int t = 0; t < SEQ / 64; ++t) {
        const int cur = t & 1;
        if (t < SEQ / 64 - 1) stage(cur ^ 1, (t + 1) * 64);
        __builtin_amdgcn_sched_barrier(0);   // pin: issue next-tile stage first

        const unsigned short* Kc = &Ks[cur][0];
        const unsigned short* Vc = &Vs[cur][0];

        // S^T = K Q^T (log2 domain): 2 kv-blocks of 32, K=128 in 8 steps
        f32x16 sc[2];
#pragma unroll
        for (int kb = 0; kb < 2; ++kb)
#pragma unroll
            for (int r = 0; r < 16; ++r) sc[kb][r] = 0.f;
#pragma unroll
        for (int ks = 0; ks < 8; ++ks) {
#pragma unroll
            for (int kb = 0; kb < 2; ++kb) {
                int row = kb * 32 + l32;
                int cb = (ks * 32 + hh * 16) ^ ((row & 7) << 4);
                bf16x8 kf = as_bf(*(const s16x8*)((const char*)Kc + row * 256 + cb));
                sc[kb] = __builtin_amdgcn_mfma_f32_32x32x16_bf16(kf, qf[ks], sc[kb], 0, 0, 0);
            }
        }

        // per-lane max over 32 values, then combine lane pair (l, l^32)
        float tmax = sc[0][0];
#pragma unroll
        for (int kb = 0; kb < 2; ++kb)
#pragma unroll
            for (int r = 0; r < 16; ++r) tmax = fmaxf(tmax, sc[kb][r]);
        tmax = fmaxf(tmax, __shfl_xor(tmax, 32, 64));

        // defer-max (T13, log2 units): skip rescale when growth <= 8
        if (!__all(tmax - mrun <= 8.0f)) {
            float mn = fmaxf(mrun, tmax);
            float e_ = exp2f(mrun - mn);
            mrun = mn;
            lrun *= e_;
            float sr[16];
#pragma unroll
            for (int r = 0; r < 16; ++r)
                sr[r] = __shfl(e_, (r & 3) + 8 * (r >> 2) + 4 * hh, 64);
#pragma unroll
            for (int db = 0; db < 4; ++db)
#pragma unroll
                for (int r = 0; r < 16; ++r) ob[db][r] *= sr[r];
        }

        // P = exp2(S - m); pack to bf16 pairs; sum
        unsigned pk[2][8];
        float sum = 0.f;
#pragma unroll
        for (int kb = 0; kb < 2; ++kb) {
#pragma unroll
            for (int g = 0; g < 8; ++g) {
                float p0 = exp2f(sc[kb][2 * g]     - mrun);
                float p1 = exp2f(sc[kb][2 * g + 1] - mrun);
                sum += p0 + p1;
                union { __bf16 b[2]; unsigned u; } w;
                w.b[0] = (__bf16)p0; w.b[1] = (__bf16)p1;
                pk[kb][g] = w.u;
            }
        }
        sum += __shfl_xor(sum, 32, 64);
        lrun += sum;

        // PV A-fragments: pa[ks] elem e -> P[q=l32][kv = ks*16 + hh*8 + e]
        union { unsigned u[4]; bf16x8 v; } pa[4];
#pragma unroll
        for (int ks = 0; ks < 4; ++ks) {
            const int kb = ks >> 1, base = (ks & 1) * 4;
            unsigned a0 = __shfl_xor(pk[kb][base + 0], 32, 64);
            unsigned a1 = __shfl_xor(pk[kb][base + 1], 32, 64);
            unsigned a2 = __shfl_xor(pk[kb][base + 2], 32, 64);
            unsigned a3 = __shfl_xor(pk[kb][base + 3], 32, 64);
            pa[ks].u[0] = hh ? a2 : pk[kb][base + 0];
            pa[ks].u[1] = hh ? a3 : pk[kb][base + 1];
            pa[ks].u[2] = hh ? pk[kb][base + 2] : a0;
            pa[ks].u[3] = hh ? pk[kb][base + 3] : a1;
        }

        // O += P V: B = V^T[d][kv] swizzled; 4 d-blocks x 4 kv-steps
#pragma unroll
        for (int ks = 0; ks < 4; ++ks) {
#pragma unroll
            for (int db = 0; db < 4; ++db) {
                int row = db * 32 + l32;
                int cb = (ks * 32 + hh * 16) ^ ((row & 7) << 4);
                bf16x8 vb = as_bf(*(const s16x8*)((const char*)Vc + row * 128 + cb));
                ob[db] = __builtin_amdgcn_mfma_f32_32x32x16_bf16(pa[ks].v, vb, ob[db], 0, 0, 0);
            }
        }
        __syncthreads();   // implicit vmcnt(0): next-tile stage (issued pre-compute) done
    }

    // stats at q=l32 lanes; ob rows are q=(r&3)+8*(r>>2)+4*hh -> hop via shuffles
    float linv = 1.f / lrun;
    float li[16];
#pragma unroll
    for (int r = 0; r < 16; ++r)
        li[r] = __shfl(linv, (r & 3) + 8 * (r >> 2) + 4 * hh, 64);
#pragma unroll
    for (int db = 0; db < 4; ++db) {
#pragma unroll
        for (int r = 0; r < 16; ++r) {
            const long m = rowbase + qt * 256 + wid * 32 + (r & 3) + 8 * (r >> 2) + 4 * hh;
            attnout[m * HID + h * HD + db * 32 + l32] = f2bf(ob[db][r] * li[r]);
        }
    }
}

// ---------------- launch ----------------
extern "C" void kernel_launch(void* const* d_in, const int* in_sizes, int n_in,
                              void* d_out, int out_size, void* d_ws, size_t ws_size,
                              hipStream_t stream)
{
    const float* hs = (const float*)d_in[0];
    const float* Wq = (const float*)d_in[1];
    const float* bq = (const float*)d_in[2];
    const float* Wk = (const float*)d_in[3];
    const float* bk = (const float*)d_in[4];
    const float* Wv = (const float*)d_in[5];
    const float* bv = (const float*)d_in[6];
    const float* Wo = (const float*)d_in[7];
    float* out = (float*)d_out;   // fp32 output (confirmed round 5)

    bool shapes_ok =
        (n_in == 8) && (out_size == 8388608) &&
        in_sizes[0] == 8388608 && in_sizes[1] == 4194304 && in_sizes[2] == 2048 &&
        in_sizes[3] == 4194304 && in_sizes[4] == 2048 && in_sizes[5] == 4194304 &&
        in_sizes[6] == 2048 && in_sizes[7] == 4194304;
    if (!shapes_ok || ws_size < 117440512ull) {
        fill_f32<<<32768, 256, 0, stream>>>(out, shapes_ok ? 1000.f : 0.f, out_size);
        return;
    }

    char* ws = (char*)d_ws;
    unsigned short* hsB     = (unsigned short*)(ws);              // [4096][2048] bf16
    unsigned short* qkvB    = (unsigned short*)(ws + 16777216);   // [4096][6144] bf16
    unsigned short* wqkvT   = (unsigned short*)(ws + 67108864);   // [6144][2048] bf16
    unsigned short* vtB     = (unsigned short*)(ws + 92274688);   // [32][128][2048] bf16
    unsigned short* woT     = (unsigned short*)(ws + 109051904);  // [2048][2048] bf16
    unsigned short* attnout = hsB;   // hsB dead after QKV GEMM

    convert_f32_bf16<<<4096, 256, 0, stream>>>(hs, hsB);
    transpose_w4<<<dim3(64, 64, 4), 256, 0, stream>>>(Wq, Wk, Wv, Wo, wqkvT, woT);

    // QKV fat-wave + fused RoPE epilogue: 256x384 tiles -> 256 blocks = 1 round
    gemm_8phase<6, false, true><<<dim3(256), 512, 0, stream>>>(
        hsB, wqkvT, bq, bk, bv, qkvB, nullptr, 2048, QKN, 16, 8, 4, 1);
    v_transpose<<<dim3(64, 4, 32), 256, 0, stream>>>(qkvB, vtB);
    // attn: 32x32 shape, QBLK=256, 8 waves x 32 q, 256 blocks = 1 round
    attn_kernel<<<dim3(256), 512, 0, stream>>>(qkvB, vtB, attnout);
    // out-proj: 256x128 tiles, 16x16 grid, XCD chunks 4x8, fp32 out
    gemm_8phase<2, true, false><<<dim3(256), 512, 0, stream>>>(
        attnout, woT, nullptr, nullptr, nullptr, nullptr, out, 2048, HID, 16, 4, 8, 0);
}